// Round 17
// baseline (485.593 us; speedup 1.0000x reference)
//
#include <hip/hip_runtime.h>
#include <hip/hip_cooperative_groups.h>

namespace cg = cooperative_groups;

// Equalization: images [64, 512, 512, 3] int32 in [0,255].
// Single cooperative kernel: per-block LDS hist -> global hist -> grid.sync
// -> per-block LUT rebuild (redundant, cheap) -> apply from LDS LUT.
// Output dtype = int32 (confirmed R11). absmax=0 verified R15.

#define NB    64
#define CH    3
#define EPI   786432                    // 512*512*3 elements per image
#define NBINS 256
#define NHIST (NB * CH)
#define GRID  1024                      // 4 blocks/CU on 256 CUs -> co-resident
#define TPB   256
#define EPB   (EPI * NB / GRID)         // 49152 elements per block
#define BPI   (EPI / EPB)               // 16 blocks per image (exact)
#define IT4   (EPB / 4 / TPB)           // 48 int4 iterations per thread

typedef int vint4 __attribute__((ext_vector_type(4)));

__global__ __launch_bounds__(TPB) void eq_fused(const int* __restrict__ in,
                                                int* __restrict__ ghist,
                                                int* __restrict__ out) {
    __shared__ int h[CH * NBINS];       // per-block histogram
    __shared__ int lut[CH * NBINS];     // per-image LUTs (phase 2/3)
    __shared__ int cs[NBINS];           // scan scratch
    __shared__ int red[NBINS];          // reduce scratch

    const int t     = threadIdx.x;
    const int b     = blockIdx.x;
    const int img   = b / BPI;
    const int chunk = b % BPI;
    const int base  = img * EPI + chunk * EPB;      // < 2^26, int ok

    // ---------------- phase 1: histogram ----------------
    for (int r = t; r < CH * NBINS; r += TPB) h[r] = 0;
    __syncthreads();

    const int4* p = (const int4*)(in + base);
    // channel of element (base + 4*t); each k-step advances 1024 elems -> +1 phase
    int ca = (base + t * 4) % 3;
    for (int k = 0; k < IT4; ++k) {
        int4 x = p[t + k * TPB];
        const int cb = (ca + 1 == 3) ? 0 : ca + 1;
        const int cc = (cb + 1 == 3) ? 0 : cb + 1;
        atomicAdd(&h[ca * NBINS + min(max(x.x, 0), 255)], 1);
        atomicAdd(&h[cb * NBINS + min(max(x.y, 0), 255)], 1);
        atomicAdd(&h[cc * NBINS + min(max(x.z, 0), 255)], 1);
        atomicAdd(&h[ca * NBINS + min(max(x.w, 0), 255)], 1);
        ca = cb;
    }
    __syncthreads();

    int* gh = ghist + img * (CH * NBINS);
    for (int r = t; r < CH * NBINS; r += TPB) {
        int v = h[r];
        if (v) atomicAdd(&gh[r], v);
    }

    // ---------------- grid-wide barrier ----------------
    cg::this_grid().sync();

    // ---------------- phase 2: rebuild LUTs (per block, t == bin index) ----
    const int* ghc = ghist + img * (CH * NBINS);
    for (int c = 0; c < CH; ++c) {
        __syncthreads();                 // protect cs/red reuse across channels
        int hval = ghc[c * NBINS + t];
        cs[t]  = hval;
        red[t] = (hval > 0) ? t : -1;
        __syncthreads();
        for (int o = 128; o >= 1; o >>= 1) {
            if (t < o) red[t] = max(red[t], red[t + o]);
            __syncthreads();
        }
        for (int o = 1; o < NBINS; o <<= 1) {
            int add = (t >= o) ? cs[t - o] : 0;
            __syncthreads();
            cs[t] += add;
            __syncthreads();
        }
        const int last     = red[0];
        const int last_val = ghc[c * NBINS + max(last, 0)];
        const int total    = cs[NBINS - 1];
        const int step     = (total - last_val) / (NBINS - 1);
        int lutv;
        if (step == 0) {
            lutv = t;                    // where(step==0, img, eq) -> identity
        } else {
            int cp = (t == 0) ? 0 : cs[t - 1];   // shifted cumsum
            lutv = min((cp + step / 2) / step, 255);
        }
        lut[c * NBINS + t] = lutv;
    }
    __syncthreads();

    // ---------------- phase 3: apply (input should be L3-resident) --------
    vint4* q = (vint4*)(out + base);
    int cb0 = (base + t * 4) % 3;
    for (int k = 0; k < IT4; ++k) {
        int4 x = p[t + k * TPB];
        const int cbb = (cb0 + 1 == 3) ? 0 : cb0 + 1;
        const int cbc = (cbb + 1 == 3) ? 0 : cbb + 1;
        vint4 y;
        y.x = lut[cb0 * NBINS + min(max(x.x, 0), 255)];
        y.y = lut[cbb * NBINS + min(max(x.y, 0), 255)];
        y.z = lut[cbc * NBINS + min(max(x.z, 0), 255)];
        y.w = lut[cb0 * NBINS + min(max(x.w, 0), 255)];
        // Output written once, never re-read: keep it out of cache so the
        // input stays L3-resident for the remaining blocks.
        __builtin_nontemporal_store(y, &q[t + k * TPB]);
        cb0 = cbb;
    }
}

extern "C" void kernel_launch(void* const* d_in, const int* in_sizes, int n_in,
                              void* d_out, int out_size, void* d_ws, size_t ws_size,
                              hipStream_t stream) {
    const int* in = (const int*)d_in[0];
    int* out   = (int*)d_out;
    int* ghist = (int*)d_ws;

    // d_ws is poisoned 0xAA before every launch — zero the histograms.
    (void)hipMemsetAsync(ghist, 0, NHIST * NBINS * sizeof(int), stream);

    void* args[] = { (void*)&in, (void*)&ghist, (void*)&out };
    (void)hipLaunchCooperativeKernel((void*)eq_fused, dim3(GRID), dim3(TPB),
                                     args, 0, stream);
}